// Round 7
// baseline (309.240 us; speedup 1.0000x reference)
//
#include <hip/hip_runtime.h>
#include <cstdint>

#define BB 4
#define SEQ 2048
#define EMB 768
#define NH 8
#define HD 96
#define E3 2304
#define MTOK 8192
#define NROWS 65536            // BB*NH*SEQ
#define KSPLIT 4
#define SCALING 0.10206207261596575f
#define LOG2E 1.44269504f

typedef unsigned short u16;
typedef unsigned int u32;
typedef __bf16 bf16x8 __attribute__((ext_vector_type(8)));
typedef float f32x4 __attribute__((ext_vector_type(4)));
typedef float f32x16 __attribute__((ext_vector_type(16)));

__device__ __forceinline__ u16 f2bf(float f) {
    union { float f; uint32_t u; } c; c.f = f;
    uint32_t u = c.u;
    return (u16)((u + 0x7FFFu + ((u >> 16) & 1u)) >> 16);
}
__device__ __forceinline__ uint32_t pk2(float a, float b) {
    return (uint32_t)f2bf(a) | ((uint32_t)f2bf(b) << 16);
}
__device__ __forceinline__ uint32_t cvtpk(float a, float b) {
    uint32_t r;
    asm("v_cvt_pk_bf16_f32 %0, %1, %2" : "=v"(r) : "v"(a), "v"(b));
    return r;
}
__device__ __forceinline__ float bf2f(u16 h) {
    union { uint32_t u; float f; } c; c.u = ((uint32_t)h) << 16; return c.f;
}
__device__ __forceinline__ float fexp2(float x) {
    return __builtin_amdgcn_exp2f(x);
}
__device__ __forceinline__ void async16(const u16* g, u16* l) {
    __builtin_amdgcn_global_load_lds(
        (const __attribute__((address_space(1))) void*)g,
        (__attribute__((address_space(3))) void*)l, 16, 0, 0);
}

// ---------------- fused prep: cvt_x + 3 weight transposes, one launch ----------------

__device__ __forceinline__ void transpose_body(const float* __restrict__ src,
                                               u16* __restrict__ dst,
                                               int ncols, int mode, int j0, int k0,
                                               int tid, float (*T)[65]) {
#pragma unroll
    for (int it = 0; it < 16; ++it) {
        int lin = it * 256 + tid;
        int rr2 = lin >> 6, jj = lin & 63;
        int j = j0 + jj;
        int c;
        if (mode == 0) c = j;
        else if (mode == 1) { int s = j / 768, rr = j % 768; c = (rr / 96) * 288 + (rr % 96) * 3 + s; }
        else { c = (j / 96) * 288 + (j % 96) * 3 + 2; }
        T[rr2][jj] = src[(k0 + rr2) * ncols + c];
    }
    __syncthreads();
#pragma unroll
    for (int it = 0; it < 16; ++it) {
        int lin = it * 256 + tid;
        int jr = lin >> 6, kc = lin & 63;
        dst[(size_t)(j0 + jr) * 768 + k0 + kc] = f2bf(T[kc][jr]);
    }
}

__global__ __launch_bounds__(256) void prep_kernel(const float* __restrict__ x,
                                                   const float* __restrict__ Wqkv,
                                                   const float* __restrict__ Wproj,
                                                   u16* __restrict__ xb,
                                                   u16* __restrict__ wqkT,
                                                   u16* __restrict__ wvr,
                                                   u16* __restrict__ wpt) {
    __shared__ float T[64][65];
    int bid = blockIdx.x, tid = threadIdx.x;
    if (bid < 3072) {
        int i = bid * 256 + tid;                    // 786432 chunks of 8 floats
        const float4* s4 = (const float4*)x;
        float4 a = s4[2 * i];
        float4 c = s4[2 * i + 1];
        uint4 o;
        o.x = pk2(a.x, a.y); o.y = pk2(a.z, a.w);
        o.z = pk2(c.x, c.y); o.w = pk2(c.z, c.w);
        ((uint4*)xb)[i] = o;
    } else if (bid < 3360) {
        int t = bid - 3072;
        transpose_body(Wqkv, wqkT, E3, 1, (t % 24) * 64, (t / 24) * 64, tid, T);
    } else if (bid < 3504) {
        int t = bid - 3360;
        transpose_body(Wqkv, wvr, E3, 2, (t % 12) * 64, (t / 12) * 64, tid, T);
    } else {
        int t = bid - 3504;
        transpose_body(Wproj, wpt, EMB, 0, (t % 12) * 64, (t / 12) * 64, tid, T);
    }
}

// ---------------- NT-GEMM mainloops: global_load_lds + XOR-swizzled LDS ----------------

// 128x128 tile
__device__ __forceinline__ void gemm_tiles(const u16* __restrict__ A,
                                           const u16* __restrict__ Bt,
                                           int m0, int n0, int tid,
                                           u16* As, u16* Bs, f32x4 acc[4][4]) {
    const int lane = tid & 63;
    const int w = tid >> 6;
    const int l15 = lane & 15;
    const int quad = lane >> 4;
    const int wr = (w >> 1) * 64;
    const int wc = (w & 1) * 64;
    const int swz = l15 & 7;
    for (int kb = 0; kb < 768; kb += 64) {
#pragma unroll
        for (int it = 0; it < 4; ++it) {
            int base = (w * 4 + it) * 64;
            int lin = base + lane;
            int row = lin >> 3, cl = lin & 7;
            int cg = cl ^ (row & 7);
            async16(&A[(size_t)(m0 + row) * 768 + kb + cg * 8], &As[base * 8]);
            async16(&Bt[(size_t)(n0 + row) * 768 + kb + cg * 8], &Bs[base * 8]);
        }
        __syncthreads();
#pragma unroll
        for (int ks = 0; ks < 2; ++ks) {
            bf16x8 af[4], bfg[4];
#pragma unroll
            for (int fi = 0; fi < 4; ++fi)
                af[fi] = *(const bf16x8*)&As[(wr + fi * 16 + l15) * 64 + (((ks * 4 + quad) ^ swz) * 8)];
#pragma unroll
            for (int fj = 0; fj < 4; ++fj)
                bfg[fj] = *(const bf16x8*)&Bs[(wc + fj * 16 + l15) * 64 + (((ks * 4 + quad) ^ swz) * 8)];
#pragma unroll
            for (int fi = 0; fi < 4; ++fi)
#pragma unroll
                for (int fj = 0; fj < 4; ++fj)
                    acc[fi][fj] = __builtin_amdgcn_mfma_f32_16x16x32_bf16(af[fi], bfg[fj], acc[fi][fj], 0, 0, 0);
        }
        __syncthreads();
    }
}

// 128x64 tile (skinny-N GEMMs)
__device__ __forceinline__ void gemm_tiles64(const u16* __restrict__ A,
                                             const u16* __restrict__ Bt,
                                             int m0, int n0, int tid,
                                             u16* As, u16* Bs, f32x4 acc[4][2]) {
    const int lane = tid & 63;
    const int w = tid >> 6;
    const int l15 = lane & 15;
    const int quad = lane >> 4;
    const int wr = (w >> 1) * 64;
    const int wc = (w & 1) * 32;
    const int swz = l15 & 7;
    for (int kb = 0; kb < 768; kb += 64) {
#pragma unroll
        for (int it = 0; it < 4; ++it) {
            int base = (w * 4 + it) * 64;
            int lin = base + lane;
            int row = lin >> 3, cl = lin & 7;
            int cg = cl ^ (row & 7);
            async16(&A[(size_t)(m0 + row) * 768 + kb + cg * 8], &As[base * 8]);
        }
#pragma unroll
        for (int it = 0; it < 2; ++it) {
            int base = (w * 2 + it) * 64;
            int lin = base + lane;
            int row = lin >> 3, cl = lin & 7;
            int cg = cl ^ (row & 7);
            async16(&Bt[(size_t)(n0 + row) * 768 + kb + cg * 8], &Bs[base * 8]);
        }
        __syncthreads();
#pragma unroll
        for (int ks = 0; ks < 2; ++ks) {
            bf16x8 af[4], bfg[2];
#pragma unroll
            for (int fi = 0; fi < 4; ++fi)
                af[fi] = *(const bf16x8*)&As[(wr + fi * 16 + l15) * 64 + (((ks * 4 + quad) ^ swz) * 8)];
#pragma unroll
            for (int fj = 0; fj < 2; ++fj)
                bfg[fj] = *(const bf16x8*)&Bs[(wc + fj * 16 + l15) * 64 + (((ks * 4 + quad) ^ swz) * 8)];
#pragma unroll
            for (int fi = 0; fi < 4; ++fi)
#pragma unroll
                for (int fj = 0; fj < 2; ++fj)
                    acc[fi][fj] = __builtin_amdgcn_mfma_f32_16x16x32_bf16(af[fi], bfg[fj], acc[fi][fj], 0, 0, 0);
        }
        __syncthreads();
    }
}

// Fused QKV projection: qk-blocks (0..767) + v-blocks (768..1535) in ONE dispatch.
// (R5-verified: total 239.4 -> 234.8 us vs split kernels.)
__global__ __launch_bounds__(256) void gemm_qkv_kernel(const u16* __restrict__ xb,
                                                       const u16* __restrict__ wqkT,
                                                       const u16* __restrict__ wvr,
                                                       const float* __restrict__ bqkv,
                                                       u16* __restrict__ qb,
                                                       u16* __restrict__ kg,
                                                       u16* __restrict__ vt) {
    __shared__ __align__(16) u16 As[128 * 64];
    __shared__ __align__(16) u16 Bs[128 * 64];   // v-path uses first 64*64
    int bid = blockIdx.x, tid = threadIdx.x;
    int lane = tid & 63, w = tid >> 6, l15 = lane & 15, quad = lane >> 4;
    if (bid < 768) {
        // ---- Q/K projection: M=8192 x N=1536. Q pre-scaled by LOG2E -> qb[bh][n][96].
        // K -> kg[bh][n][128], chunk-swizzled. Bias permute inline.
        int n0 = (bid % 12) * 128, m0 = (bid / 12) * 128;
        f32x4 acc[4][4] = {};
        gemm_tiles(xb, wqkT, m0, n0, tid, As, Bs, acc);
        int wr = (w >> 1) * 64, wc = (w & 1) * 64;
#pragma unroll
        for (int fj = 0; fj < 4; ++fj) {
            int j = n0 + wc + fj * 16 + l15;
            int s = j / 768, rr = j % 768;
            int hh = rr / 96, dd = rr % 96;
            float bv = bqkv[hh * 288 + dd * 3 + s];
#pragma unroll
            for (int fi = 0; fi < 4; ++fi) {
#pragma unroll
                for (int r = 0; r < 4; ++r) {
                    int m = m0 + wr + fi * 16 + quad * 4 + r;
                    int b = m >> 11, n = m & 2047;
                    int bh = b * NH + hh;
                    float v = acc[fi][fj][r] + bv;
                    if (s == 0) {
                        qb[((size_t)bh * SEQ + n) * HD + dd] = f2bf(v * LOG2E);
                    } else {
                        int cp = (dd >> 3) ^ (n & 7);
                        kg[((size_t)bh * SEQ + n) * 128 + cp * 8 + (dd & 7)] = f2bf(v);
                    }
                }
            }
        }
    } else {
        // ---- V projection, transposed: C[dd_global][token], chunk-swizzled token idx.
        int t = bid - 768;
        int n0 = (t % 128) * 64, m0 = (t / 128) * 128;
        f32x4 acc[4][2] = {};
        gemm_tiles64(wvr, xb, m0, n0, tid, As, Bs, acc);
        int wr = (w >> 1) * 64, wc = (w & 1) * 32;
        float bvs[4][4]; int hhs[4][4], dds[4][4];
#pragma unroll
        for (int fi = 0; fi < 4; ++fi)
#pragma unroll
            for (int r = 0; r < 4; ++r) {
                int m = m0 + wr + fi * 16 + quad * 4 + r;
                int hh = m / 96, dd = m % 96;
                hhs[fi][r] = hh; dds[fi][r] = dd;
                bvs[fi][r] = bqkv[hh * 288 + dd * 3 + 2];
            }
#pragma unroll
        for (int fj = 0; fj < 2; ++fj) {
            int n = n0 + wc + fj * 16 + l15;
            int b = n >> 11, nn = n & 2047;
#pragma unroll
            for (int fi = 0; fi < 4; ++fi) {
#pragma unroll
                for (int r = 0; r < 4; ++r) {
                    int dd = dds[fi][r];
                    int kk = (nn & ~63) | ((((nn >> 3) ^ dd) & 7) << 3) | (nn & 7);
                    vt[((size_t)(b * NH + hhs[fi][r]) * HD + dd) * SEQ + kk] =
                        f2bf(acc[fi][fj][r] + bvs[fi][r]);
                }
            }
        }
    }
}

// out projection: 128(M)x64(N) tiles, grid 12x64 = 768 = 3/CU even.
__global__ __launch_bounds__(256) void gemm_proj_kernel(const u16* __restrict__ A,
                                                        const u16* __restrict__ Bt,
                                                        const float* __restrict__ bias,
                                                        float* __restrict__ out) {
    __shared__ __align__(16) u16 As[128 * 64];
    __shared__ __align__(16) u16 Bs[64 * 64];
    int tid = threadIdx.x;
    int n0 = blockIdx.x * 64, m0 = blockIdx.y * 128;
    f32x4 acc[4][2] = {};
    gemm_tiles64(A, Bt, m0, n0, tid, As, Bs, acc);
    int lane = tid & 63, w = tid >> 6, l15 = lane & 15, quad = lane >> 4;
    int wr = (w >> 1) * 64, wc = (w & 1) * 32;
#pragma unroll
    for (int fj = 0; fj < 2; ++fj) {
        int j = n0 + wc + fj * 16 + l15;
        float bv = bias[j];
#pragma unroll
        for (int fi = 0; fi < 4; ++fi) {
#pragma unroll
            for (int r = 0; r < 4; ++r) {
                int m = m0 + wr + fi * 16 + quad * 4 + r;
                out[(size_t)m * 768 + j] = acc[fi][fj][r] + bv;
            }
        }
    }
}

// ---------------- flash attention: 8 waves x 1 q-tile, DOUBLE-buffered, XCD-pinned ---
// R7 EXPERIMENT: R6 proved TLP is saturated (2x occupancy, flat time) -> the ~2.5k
// cy/tile stall is the serial stage -> barrier(vmcnt drain) -> compute chain. Fix:
// K/V ping-pong double-buffer (57 KB). Unlike R1 (which dbuf'd 4-wave blocks and
// dropped to 8 waves/CU, regressing), the 8-wave/1-q-tile block is VGPR-light
// (~112/wave incl acc -> 4 waves/SIMD allowed), so 2 blocks/CU x 8 waves = 16
// waves/CU — R5-equivalent TLP retained. One barrier per tile; prefetch issued
// BEFORE compute so its vmcnt-drain at the barrier lands a full compute-phase after
// issue (L2 latency hidden). Softmax: cvt_pk + permlane32_swap + setprio (R3).
// Grid idx = qt*128 + bh*4 + kh -> same-XCD K/V slice sharing (L2).
__global__ __launch_bounds__(512, 4) void attn_kernel(const u16* __restrict__ Q,
                                                      const u16* __restrict__ Kg,
                                                      const u16* __restrict__ Vt,
                                                      u16* __restrict__ part,
                                                      float* __restrict__ lpart) {
    __shared__ __align__(16) u16 Ks[2 * 64 * 128];   // 32 KB
    __shared__ __align__(16) u16 Vs[2 * 96 * 64];    // 24 KB
    int tid = threadIdx.x;
    int lane = tid & 63, w = tid >> 6;           // w = 0..7
    int l31 = lane & 31, hf = lane >> 5;
    int swz = l31 & 7;
    int bid = blockIdx.x;
    int qt = bid >> 7;                 // 0..7
    int g = bid & 127;
    int bh = g >> 2, kh = g & 3;       // (bh,kh) fixed -> idx%8 fixed -> same XCD
    const u16* qp = Q + (size_t)bh * SEQ * HD;
    const u16* kgp = Kg + (size_t)bh * SEQ * 128;
    const u16* vtp = Vt + (size_t)bh * HD * SEQ;
    int qbase = qt * 256 + w * 32;     // each wave owns ONE 32-q tile
    int kbase = kh * 512;

    // Q B-operand frags: 6 d-chunks, in registers for whole kernel
    bf16x8 aq[6];
#pragma unroll
    for (int dc = 0; dc < 6; ++dc)
        aq[dc] = *(const bf16x8*)&qp[(size_t)(qbase + l31) * HD + dc * 16 + hf * 8];

    f32x16 Ot[3] = {};
    float lp = 0.f;

    u16* Ks0 = Ks;            u16* Ks1 = Ks + 64 * 128;
    u16* Vs0 = Vs;            u16* Vs1 = Vs + 96 * 64;

    // stage K/V tile kt; staging split over 8 waves (K 16 chunks, V 12 chunks)
    auto STAGE = [&](int kt, u16* kdst, u16* vdst) {
        int k0 = kbase + kt * 64;
#pragma unroll
        for (int it = 0; it < 2; ++it) {
            int cw = w * 2 + it;
            async16(kgp + (size_t)(k0 + cw * 4 + (lane >> 4)) * 128 + (lane & 15) * 8,
                    &kdst[cw * 512]);
        }
#pragma unroll
        for (int it = 0; it < 2; ++it) {
            int vw = it * 8 + w;
            if (vw < 12)
                async16(vtp + (size_t)(vw * 8 + (lane >> 3)) * SEQ + k0 + (lane & 7) * 8,
                        &vdst[vw * 512]);
        }
    };

    // full compute on one staged 64-key tile
    auto COMPUTE = [&](const u16* ksrc, const u16* vsrc) {
#pragma unroll
        for (int tau = 0; tau < 2; ++tau) {
            f32x16 Sv = {};
            __builtin_amdgcn_s_setprio(1);
#pragma unroll
            for (int dc = 0; dc < 6; ++dc) {
                bf16x8 ka = *(const bf16x8*)&ksrc[(tau * 32 + l31) * 128 + (((2 * dc + hf) ^ swz) * 8)];
                Sv = __builtin_amdgcn_mfma_f32_32x32x16_bf16(ka, aq[dc], Sv, 0, 0, 0);
            }
            __builtin_amdgcn_s_setprio(0);
            u32 pk[4][2];
#pragma unroll
            for (int g2 = 0; g2 < 4; ++g2)
#pragma unroll
                for (int u = 0; u < 2; ++u) {
                    float a0 = fexp2(Sv[g2 * 4 + 2 * u]);
                    float a1 = fexp2(Sv[g2 * 4 + 2 * u + 1]);
                    lp += a0 + a1;
                    pk[g2][u] = cvtpk(a0, a1);
                }
            // cross-half exchange: v_permlane32_swap_b32(X=pk[2kc], Y=pk[2kc+1]) gives
            //   X' = pf words 0/1, Y' = pf words 2/3 for all lanes
#pragma unroll
            for (int kc = 0; kc < 2; ++kc)
#pragma unroll
                for (int u = 0; u < 2; ++u)
                    asm("v_permlane32_swap_b32 %0, %1"
                        : "+v"(pk[2 * kc][u]), "+v"(pk[2 * kc + 1][u]));
#pragma unroll
            for (int kc = 0; kc < 2; ++kc) {
                union { u32 u[4]; bf16x8 v; } pf;
                pf.u[0] = pk[2 * kc][0];     pf.u[1] = pk[2 * kc][1];
                pf.u[2] = pk[2 * kc + 1][0]; pf.u[3] = pk[2 * kc + 1][1];
                __builtin_amdgcn_s_setprio(1);
#pragma unroll
                for (int t = 0; t < 3; ++t) {
                    bf16x8 va = *(const bf16x8*)&vsrc[(t * 32 + l31) * 64 + (((4 * tau + 2 * kc + hf) ^ swz) * 8)];
                    Ot[t] = __builtin_amdgcn_mfma_f32_32x32x16_bf16(va, pf.v, Ot[t], 0, 0, 0);
                }
                __builtin_amdgcn_s_setprio(0);
            }
        }
    };

    STAGE(0, Ks0, Vs0);
    __syncthreads();
    for (int kt = 0; kt < 8; kt += 2) {
        if (kt < 7) STAGE(kt + 1, Ks1, Vs1);   // prefetch overlaps compute below
        COMPUTE(Ks0, Vs0);
        __syncthreads();                        // one barrier/tile; drains prefetch
        if (kt < 6) STAGE(kt + 2, Ks0, Vs0);
        COMPUTE(Ks1, Vs1);
        __syncthreads();
    }

    // epilogue: bf16 partial O^T + f32 partial l
    size_t pb = (size_t)kh * NROWS + (size_t)bh * SEQ;
    {
        int q = qbase + l31;
        float lr = lp + __shfl_xor(lp, 32);
        if (hf == 0) lpart[pb + q] = lr;
        size_t rowb = (pb + q) * HD;
#pragma unroll
        for (int t = 0; t < 3; ++t) {
#pragma unroll
            for (int g2 = 0; g2 < 4; ++g2) {
                int d0 = t * 32 + 8 * g2 + 4 * hf;
                uint2 val;
                val.x = pk2(Ot[t][g2 * 4 + 0], Ot[t][g2 * 4 + 1]);
                val.y = pk2(Ot[t][g2 * 4 + 2], Ot[t][g2 * 4 + 3]);
                *(uint2*)&part[rowb + d0] = val;
            }
        }
    }
}

// combine: ao[b][n][h*96+d] = (sum_kh part_kh) * SCALING / (sum_kh l_kh)
__global__ __launch_bounds__(256) void combine_kernel(const u16* __restrict__ part,
                                                      const float* __restrict__ lpart,
                                                      u16* __restrict__ ao) {
    int idx = blockIdx.x * 256 + threadIdx.x;       // NROWS*12 threads
    int row = idx / 12, ch = idx % 12;
    float l = 0.f;
#pragma unroll
    for (int k = 0; k < KSPLIT; ++k) l += lpart[(size_t)k * NROWS + row];
    float sc = SCALING / l;
    float acc[8] = {};
#pragma unroll
    for (int k = 0; k < KSPLIT; ++k) {
        uint4 pv = *(const uint4*)&part[((size_t)k * NROWS + row) * HD + ch * 8];
        const u16* a = (const u16*)&pv;
#pragma unroll
        for (int i = 0; i < 8; ++i) acc[i] += bf2f(a[i]);
    }
    uint4 o;
    u32* ou = (u32*)&o;
#pragma unroll
    for (int i = 0; i < 4; ++i)
        ou[i] = pk2(acc[2 * i] * sc, acc[2 * i + 1] * sc);
    int bh = row >> 11, n = row & 2047;
    int b = bh >> 3, h = bh & 7;
    *(uint4*)&ao[((size_t)(b * SEQ + n)) * EMB + h * HD + ch * 8] = o;
}

// ---------------- launch ----------------

extern "C" void kernel_launch(void* const* d_in, const int* in_sizes, int n_in,
                              void* d_out, int out_size, void* d_ws, size_t ws_size,
                              hipStream_t stream) {
    const float* x     = (const float*)d_in[0];
    const float* Wqkv  = (const float*)d_in[1];
    const float* bqkv  = (const float*)d_in[2];
    const float* Wproj = (const float*)d_in[3];
    const float* bproj = (const float*)d_in[4];
    float* out = (float*)d_out;

    // workspace: persistent buffers, then a union region (xb/wqkT/wvr alias partb:
    // xb & weights are dead once attn starts; partb is written by attn).
    char* p = (char*)d_ws;
    u16*   qb    = (u16*)p;  p += (size_t)NROWS * HD * 2;          // 12.6 MB
    u16*   kg    = (u16*)p;  p += (size_t)NROWS * 128 * 2;         // 16.8 MB
    u16*   vt    = (u16*)p;  p += (size_t)NROWS * HD * 2;          // 12.6 MB
    u16*   ao    = (u16*)p;  p += (size_t)MTOK * EMB * 2;          // 12.6 MB
    u16*   wpt   = (u16*)p;  p += (size_t)EMB * EMB * 2;           // 1.2 MB
    float* lpart = (float*)p; p += (size_t)KSPLIT * NROWS * 4;     // 1.05 MB
    char*  U     = p;                                              // union region
    u16*   xb    = (u16*)U;
    u16*   wqkT  = (u16*)(U + (size_t)MTOK * EMB * 2);
    u16*   wvr   = (u16*)(U + (size_t)MTOK * EMB * 2 + (size_t)1536 * EMB * 2);
    u16*   partb = (u16*)U;                                        // 50.3 MB

    prep_kernel<<<3648, 256, 0, stream>>>(x, Wqkv, Wproj, xb, wqkT, wvr, wpt);
    gemm_qkv_kernel<<<1536, 256, 0, stream>>>(xb, wqkT, wvr, bqkv, qb, kg, vt);
    attn_kernel<<<8 * 32 * KSPLIT, 512, 0, stream>>>(qb, kg, vt, partb, lpart);
    combine_kernel<<<NROWS * 12 / 256, 256, 0, stream>>>(partb, lpart, ao);
    gemm_proj_kernel<<<dim3(EMB / 64, MTOK / 128), 256, 0, stream>>>(ao, wpt, bproj, out);
}

// Round 8
// 236.986 us; speedup vs baseline: 1.3049x; 1.3049x over previous
//
#include <hip/hip_runtime.h>
#include <cstdint>

#define BB 4
#define SEQ 2048
#define EMB 768
#define NH 8
#define HD 96
#define E3 2304
#define MTOK 8192
#define NROWS 65536            // BB*NH*SEQ
#define KSPLIT 4
#define SCALING 0.10206207261596575f
#define LOG2E 1.44269504f

typedef unsigned short u16;
typedef unsigned int u32;
typedef __bf16 bf16x8 __attribute__((ext_vector_type(8)));
typedef float f32x4 __attribute__((ext_vector_type(4)));
typedef float f32x16 __attribute__((ext_vector_type(16)));

__device__ __forceinline__ u16 f2bf(float f) {
    union { float f; uint32_t u; } c; c.f = f;
    uint32_t u = c.u;
    return (u16)((u + 0x7FFFu + ((u >> 16) & 1u)) >> 16);
}
__device__ __forceinline__ uint32_t pk2(float a, float b) {
    return (uint32_t)f2bf(a) | ((uint32_t)f2bf(b) << 16);
}
__device__ __forceinline__ uint32_t cvtpk(float a, float b) {
    uint32_t r;
    asm("v_cvt_pk_bf16_f32 %0, %1, %2" : "=v"(r) : "v"(a), "v"(b));
    return r;
}
__device__ __forceinline__ float bf2f(u16 h) {
    union { uint32_t u; float f; } c; c.u = ((uint32_t)h) << 16; return c.f;
}
__device__ __forceinline__ float fexp2(float x) {
    return __builtin_amdgcn_exp2f(x);
}
__device__ __forceinline__ void async16(const u16* g, u16* l) {
    __builtin_amdgcn_global_load_lds(
        (const __attribute__((address_space(1))) void*)g,
        (__attribute__((address_space(3))) void*)l, 16, 0, 0);
}

// ---------------- fused prep: cvt_x + 3 weight transposes, one launch ----------------

__device__ __forceinline__ void transpose_body(const float* __restrict__ src,
                                               u16* __restrict__ dst,
                                               int ncols, int mode, int j0, int k0,
                                               int tid, float (*T)[65]) {
#pragma unroll
    for (int it = 0; it < 16; ++it) {
        int lin = it * 256 + tid;
        int rr2 = lin >> 6, jj = lin & 63;
        int j = j0 + jj;
        int c;
        if (mode == 0) c = j;
        else if (mode == 1) { int s = j / 768, rr = j % 768; c = (rr / 96) * 288 + (rr % 96) * 3 + s; }
        else { c = (j / 96) * 288 + (j % 96) * 3 + 2; }
        T[rr2][jj] = src[(k0 + rr2) * ncols + c];
    }
    __syncthreads();
#pragma unroll
    for (int it = 0; it < 16; ++it) {
        int lin = it * 256 + tid;
        int jr = lin >> 6, kc = lin & 63;
        dst[(size_t)(j0 + jr) * 768 + k0 + kc] = f2bf(T[kc][jr]);
    }
}

__global__ __launch_bounds__(256) void prep_kernel(const float* __restrict__ x,
                                                   const float* __restrict__ Wqkv,
                                                   const float* __restrict__ Wproj,
                                                   u16* __restrict__ xb,
                                                   u16* __restrict__ wqkT,
                                                   u16* __restrict__ wvr,
                                                   u16* __restrict__ wpt) {
    __shared__ float T[64][65];
    int bid = blockIdx.x, tid = threadIdx.x;
    if (bid < 3072) {
        int i = bid * 256 + tid;                    // 786432 chunks of 8 floats
        const float4* s4 = (const float4*)x;
        float4 a = s4[2 * i];
        float4 c = s4[2 * i + 1];
        uint4 o;
        o.x = pk2(a.x, a.y); o.y = pk2(a.z, a.w);
        o.z = pk2(c.x, c.y); o.w = pk2(c.z, c.w);
        ((uint4*)xb)[i] = o;
    } else if (bid < 3360) {
        int t = bid - 3072;
        transpose_body(Wqkv, wqkT, E3, 1, (t % 24) * 64, (t / 24) * 64, tid, T);
    } else if (bid < 3504) {
        int t = bid - 3360;
        transpose_body(Wqkv, wvr, E3, 2, (t % 12) * 64, (t / 12) * 64, tid, T);
    } else {
        int t = bid - 3504;
        transpose_body(Wproj, wpt, EMB, 0, (t % 12) * 64, (t / 12) * 64, tid, T);
    }
}

// ---------------- NT-GEMM mainloops: global_load_lds + XOR-swizzled LDS ----------------

// 128x128 tile
__device__ __forceinline__ void gemm_tiles(const u16* __restrict__ A,
                                           const u16* __restrict__ Bt,
                                           int m0, int n0, int tid,
                                           u16* As, u16* Bs, f32x4 acc[4][4]) {
    const int lane = tid & 63;
    const int w = tid >> 6;
    const int l15 = lane & 15;
    const int quad = lane >> 4;
    const int wr = (w >> 1) * 64;
    const int wc = (w & 1) * 64;
    const int swz = l15 & 7;
    for (int kb = 0; kb < 768; kb += 64) {
#pragma unroll
        for (int it = 0; it < 4; ++it) {
            int base = (w * 4 + it) * 64;
            int lin = base + lane;
            int row = lin >> 3, cl = lin & 7;
            int cg = cl ^ (row & 7);
            async16(&A[(size_t)(m0 + row) * 768 + kb + cg * 8], &As[base * 8]);
            async16(&Bt[(size_t)(n0 + row) * 768 + kb + cg * 8], &Bs[base * 8]);
        }
        __syncthreads();
#pragma unroll
        for (int ks = 0; ks < 2; ++ks) {
            bf16x8 af[4], bfg[4];
#pragma unroll
            for (int fi = 0; fi < 4; ++fi)
                af[fi] = *(const bf16x8*)&As[(wr + fi * 16 + l15) * 64 + (((ks * 4 + quad) ^ swz) * 8)];
#pragma unroll
            for (int fj = 0; fj < 4; ++fj)
                bfg[fj] = *(const bf16x8*)&Bs[(wc + fj * 16 + l15) * 64 + (((ks * 4 + quad) ^ swz) * 8)];
#pragma unroll
            for (int fi = 0; fi < 4; ++fi)
#pragma unroll
                for (int fj = 0; fj < 4; ++fj)
                    acc[fi][fj] = __builtin_amdgcn_mfma_f32_16x16x32_bf16(af[fi], bfg[fj], acc[fi][fj], 0, 0, 0);
        }
        __syncthreads();
    }
}

// 128x64 tile (skinny-N GEMMs)
__device__ __forceinline__ void gemm_tiles64(const u16* __restrict__ A,
                                             const u16* __restrict__ Bt,
                                             int m0, int n0, int tid,
                                             u16* As, u16* Bs, f32x4 acc[4][2]) {
    const int lane = tid & 63;
    const int w = tid >> 6;
    const int l15 = lane & 15;
    const int quad = lane >> 4;
    const int wr = (w >> 1) * 64;
    const int wc = (w & 1) * 32;
    const int swz = l15 & 7;
    for (int kb = 0; kb < 768; kb += 64) {
#pragma unroll
        for (int it = 0; it < 4; ++it) {
            int base = (w * 4 + it) * 64;
            int lin = base + lane;
            int row = lin >> 3, cl = lin & 7;
            int cg = cl ^ (row & 7);
            async16(&A[(size_t)(m0 + row) * 768 + kb + cg * 8], &As[base * 8]);
        }
#pragma unroll
        for (int it = 0; it < 2; ++it) {
            int base = (w * 2 + it) * 64;
            int lin = base + lane;
            int row = lin >> 3, cl = lin & 7;
            int cg = cl ^ (row & 7);
            async16(&Bt[(size_t)(n0 + row) * 768 + kb + cg * 8], &Bs[base * 8]);
        }
        __syncthreads();
#pragma unroll
        for (int ks = 0; ks < 2; ++ks) {
            bf16x8 af[4], bfg[2];
#pragma unroll
            for (int fi = 0; fi < 4; ++fi)
                af[fi] = *(const bf16x8*)&As[(wr + fi * 16 + l15) * 64 + (((ks * 4 + quad) ^ swz) * 8)];
#pragma unroll
            for (int fj = 0; fj < 2; ++fj)
                bfg[fj] = *(const bf16x8*)&Bs[(wc + fj * 16 + l15) * 64 + (((ks * 4 + quad) ^ swz) * 8)];
#pragma unroll
            for (int fi = 0; fi < 4; ++fi)
#pragma unroll
                for (int fj = 0; fj < 2; ++fj)
                    acc[fi][fj] = __builtin_amdgcn_mfma_f32_16x16x32_bf16(af[fi], bfg[fj], acc[fi][fj], 0, 0, 0);
        }
        __syncthreads();
    }
}

// Unified QKV projection: ONE NT-GEMM M=8192 x N=2304 x K=768 in 128x128 tiles.
// wqkT (1536x768) and wvr (768x768) are CONTIGUOUS in the workspace, forming one
// 2304-row B^T. Grid 18x64 = 1152 blocks <= 1280 capacity (5 blocks/CU @ 32 KB LDS)
// -> single co-resident round, no straggler tail (old: 1536 blocks, V-half on
// inefficient 128x64 tiles). Epilogue branch is block-uniform: bx<12 -> Q/K path,
// bx>=12 -> V path (store to vt[dd][token] with chunk-swizzled token; consecutive
// tokens -> contiguous 8-chunks, better coalescing than the old dd-walk).
__global__ __launch_bounds__(256) void gemm_qkv_kernel(const u16* __restrict__ xb,
                                                       const u16* __restrict__ wqkT,
                                                       const float* __restrict__ bqkv,
                                                       u16* __restrict__ qb,
                                                       u16* __restrict__ kg,
                                                       u16* __restrict__ vt) {
    __shared__ __align__(16) u16 As[128 * 64];
    __shared__ __align__(16) u16 Bs[128 * 64];
    int tid = threadIdx.x;
    int n0 = blockIdx.x * 128, m0 = blockIdx.y * 128;
    f32x4 acc[4][4] = {};
    gemm_tiles(xb, wqkT, m0, n0, tid, As, Bs, acc);
    int lane = tid & 63, w = tid >> 6, l15 = lane & 15, quad = lane >> 4;
    int wr = (w >> 1) * 64, wc = (w & 1) * 64;
    if (n0 < 1536) {
        // ---- Q/K path: Q pre-scaled by LOG2E -> qb[bh][n][96]; K -> kg chunk-swizzled.
#pragma unroll
        for (int fj = 0; fj < 4; ++fj) {
            int j = n0 + wc + fj * 16 + l15;
            int s = j / 768, rr = j % 768;
            int hh = rr / 96, dd = rr % 96;
            float bv = bqkv[hh * 288 + dd * 3 + s];
#pragma unroll
            for (int fi = 0; fi < 4; ++fi) {
#pragma unroll
                for (int r = 0; r < 4; ++r) {
                    int m = m0 + wr + fi * 16 + quad * 4 + r;
                    int b = m >> 11, n = m & 2047;
                    int bh = b * NH + hh;
                    float v = acc[fi][fj][r] + bv;
                    if (s == 0) {
                        qb[((size_t)bh * SEQ + n) * HD + dd] = f2bf(v * LOG2E);
                    } else {
                        int cp = (dd >> 3) ^ (n & 7);
                        kg[((size_t)bh * SEQ + n) * 128 + cp * 8 + (dd & 7)] = f2bf(v);
                    }
                }
            }
        }
    } else {
        // ---- V path: channel c = j-1536 -> (hh,dd); token m -> chunk-swizzled kk.
#pragma unroll
        for (int fj = 0; fj < 4; ++fj) {
            int c = n0 + wc + fj * 16 + l15 - 1536;
            int hh = c / 96, dd = c % 96;
            float bv = bqkv[hh * 288 + dd * 3 + 2];
            size_t rowb = ((size_t)hh * HD + dd) * SEQ;   // + b*NH*HD*SEQ below
#pragma unroll
            for (int fi = 0; fi < 4; ++fi) {
#pragma unroll
                for (int r = 0; r < 4; ++r) {
                    int m = m0 + wr + fi * 16 + quad * 4 + r;
                    int b = m >> 11, nn = m & 2047;
                    int kk = (nn & ~63) | ((((nn >> 3) ^ dd) & 7) << 3) | (nn & 7);
                    vt[(size_t)b * NH * HD * SEQ + rowb + kk] =
                        f2bf(acc[fi][fj][r] + bv);
                }
            }
        }
    }
}

// out projection: 128(M)x64(N) tiles, grid 12x64 = 768 = 3/CU even.
__global__ __launch_bounds__(256) void gemm_proj_kernel(const u16* __restrict__ A,
                                                        const u16* __restrict__ Bt,
                                                        const float* __restrict__ bias,
                                                        float* __restrict__ out) {
    __shared__ __align__(16) u16 As[128 * 64];
    __shared__ __align__(16) u16 Bs[64 * 64];
    int tid = threadIdx.x;
    int n0 = blockIdx.x * 64, m0 = blockIdx.y * 128;
    f32x4 acc[4][2] = {};
    gemm_tiles64(A, Bt, m0, n0, tid, As, Bs, acc);
    int lane = tid & 63, w = tid >> 6, l15 = lane & 15, quad = lane >> 4;
    int wr = (w >> 1) * 64, wc = (w & 1) * 32;
#pragma unroll
    for (int fj = 0; fj < 2; ++fj) {
        int j = n0 + wc + fj * 16 + l15;
        float bv = bias[j];
#pragma unroll
        for (int fi = 0; fi < 4; ++fi) {
#pragma unroll
            for (int r = 0; r < 4; ++r) {
                int m = m0 + wr + fi * 16 + quad * 4 + r;
                out[(size_t)m * 768 + j] = acc[fi][fj][r] + bv;
            }
        }
    }
}

// ---------------- flash attention: 8 waves x 1 q-tile, 4-way K-split, XCD-pinned -----
// R6-verified structure (72.3 us), FROZEN: single-buffered 28.5 KB LDS + lockstep
// barrier cadence IS the L2-reuse mechanism — R7's double-buffer broke slice-cohort
// lockstep and quintupled FETCH (62->334 MB, HBM-bound, 150 us). 8 waves x 1 q-tile
// keeps VGPR at 64 (occupancy 35%, TLP-saturated per R6). Softmax: v_cvt_pk_bf16_f32
// + v_permlane32_swap_b32 + s_setprio (R3). Grid idx = qt*128 + bh*4 + kh -> the 8
// qt-blocks sharing a (bh,kh) K/V slice land on the same XCD (slice set fits 4MB L2).
__global__ __launch_bounds__(512, 4) void attn_kernel(const u16* __restrict__ Q,
                                                      const u16* __restrict__ Kg,
                                                      const u16* __restrict__ Vt,
                                                      u16* __restrict__ part,
                                                      float* __restrict__ lpart) {
    __shared__ __align__(16) u16 Ks[64 * 128];   // 16 KB
    __shared__ __align__(16) u16 Vs[96 * 64];    // 12 KB
    int tid = threadIdx.x;
    int lane = tid & 63, w = tid >> 6;           // w = 0..7
    int l31 = lane & 31, hf = lane >> 5;
    int swz = l31 & 7;
    int bid = blockIdx.x;
    int qt = bid >> 7;                 // 0..7
    int g = bid & 127;
    int bh = g >> 2, kh = g & 3;       // (bh,kh) fixed -> idx%8 fixed -> same XCD
    const u16* qp = Q + (size_t)bh * SEQ * HD;
    const u16* kgp = Kg + (size_t)bh * SEQ * 128;
    const u16* vtp = Vt + (size_t)bh * HD * SEQ;
    int qbase = qt * 256 + w * 32;     // each wave owns ONE 32-q tile
    int kbase = kh * 512;

    // Q B-operand frags: 6 d-chunks, in registers for whole kernel
    bf16x8 aq[6];
#pragma unroll
    for (int dc = 0; dc < 6; ++dc)
        aq[dc] = *(const bf16x8*)&qp[(size_t)(qbase + l31) * HD + dc * 16 + hf * 8];

    f32x16 Ot[3] = {};
    float lp = 0.f;

    for (int kt = 0; kt < 8; ++kt) {
        int k0 = kbase + kt * 64;
        // K: 16 chunks of 512 u16 over 8 waves
#pragma unroll
        for (int it = 0; it < 2; ++it) {
            int cw = w * 2 + it;
            async16(kgp + (size_t)(k0 + cw * 4 + (lane >> 4)) * 128 + (lane & 15) * 8,
                    &Ks[cw * 512]);
        }
        // V: 12 chunks of 512 u16 over 8 waves (waves 4..7 skip second issue)
#pragma unroll
        for (int it = 0; it < 2; ++it) {
            int vw = it * 8 + w;
            if (vw < 12)
                async16(vtp + (size_t)(vw * 8 + (lane >> 3)) * SEQ + k0 + (lane & 7) * 8,
                        &Vs[vw * 512]);
        }
        __syncthreads();

        // per 32-key group tau: S' -> exp -> permlane exchange -> PV
#pragma unroll
        for (int tau = 0; tau < 2; ++tau) {
            f32x16 Sv = {};
            __builtin_amdgcn_s_setprio(1);
#pragma unroll
            for (int dc = 0; dc < 6; ++dc) {
                bf16x8 ka = *(const bf16x8*)&Ks[(tau * 32 + l31) * 128 + (((2 * dc + hf) ^ swz) * 8)];
                Sv = __builtin_amdgcn_mfma_f32_32x32x16_bf16(ka, aq[dc], Sv, 0, 0, 0);
            }
            __builtin_amdgcn_s_setprio(0);
            u32 pk[4][2];
#pragma unroll
            for (int g2 = 0; g2 < 4; ++g2)
#pragma unroll
                for (int u = 0; u < 2; ++u) {
                    float a0 = fexp2(Sv[g2 * 4 + 2 * u]);
                    float a1 = fexp2(Sv[g2 * 4 + 2 * u + 1]);
                    lp += a0 + a1;
                    pk[g2][u] = cvtpk(a0, a1);
                }
            // cross-half exchange: v_permlane32_swap_b32(X=pk[2kc], Y=pk[2kc+1]) gives
            //   X' = pf words 0/1, Y' = pf words 2/3 for all lanes
#pragma unroll
            for (int kc = 0; kc < 2; ++kc)
#pragma unroll
                for (int u = 0; u < 2; ++u)
                    asm("v_permlane32_swap_b32 %0, %1"
                        : "+v"(pk[2 * kc][u]), "+v"(pk[2 * kc + 1][u]));
#pragma unroll
            for (int kc = 0; kc < 2; ++kc) {
                union { u32 u[4]; bf16x8 v; } pf;
                pf.u[0] = pk[2 * kc][0];     pf.u[1] = pk[2 * kc][1];
                pf.u[2] = pk[2 * kc + 1][0]; pf.u[3] = pk[2 * kc + 1][1];
                __builtin_amdgcn_s_setprio(1);
#pragma unroll
                for (int t = 0; t < 3; ++t) {
                    bf16x8 va = *(const bf16x8*)&Vs[(t * 32 + l31) * 64 + (((4 * tau + 2 * kc + hf) ^ swz) * 8)];
                    Ot[t] = __builtin_amdgcn_mfma_f32_32x32x16_bf16(va, pf.v, Ot[t], 0, 0, 0);
                }
                __builtin_amdgcn_s_setprio(0);
            }
        }
        __syncthreads();
    }

    // epilogue: bf16 partial O^T + f32 partial l
    size_t pb = (size_t)kh * NROWS + (size_t)bh * SEQ;
    {
        int q = qbase + l31;
        float lr = lp + __shfl_xor(lp, 32);
        if (hf == 0) lpart[pb + q] = lr;
        size_t rowb = (pb + q) * HD;
#pragma unroll
        for (int t = 0; t < 3; ++t) {
#pragma unroll
            for (int g2 = 0; g2 < 4; ++g2) {
                int d0 = t * 32 + 8 * g2 + 4 * hf;
                uint2 val;
                val.x = pk2(Ot[t][g2 * 4 + 0], Ot[t][g2 * 4 + 1]);
                val.y = pk2(Ot[t][g2 * 4 + 2], Ot[t][g2 * 4 + 3]);
                *(uint2*)&part[rowb + d0] = val;
            }
        }
    }
}

// combine: ao[b][n][h*96+d] = (sum_kh part_kh) * SCALING / (sum_kh l_kh)
__global__ __launch_bounds__(256) void combine_kernel(const u16* __restrict__ part,
                                                      const float* __restrict__ lpart,
                                                      u16* __restrict__ ao) {
    int idx = blockIdx.x * 256 + threadIdx.x;       // NROWS*12 threads
    int row = idx / 12, ch = idx % 12;
    float l = 0.f;
#pragma unroll
    for (int k = 0; k < KSPLIT; ++k) l += lpart[(size_t)k * NROWS + row];
    float sc = SCALING / l;
    float acc[8] = {};
#pragma unroll
    for (int k = 0; k < KSPLIT; ++k) {
        uint4 pv = *(const uint4*)&part[((size_t)k * NROWS + row) * HD + ch * 8];
        const u16* a = (const u16*)&pv;
#pragma unroll
        for (int i = 0; i < 8; ++i) acc[i] += bf2f(a[i]);
    }
    uint4 o;
    u32* ou = (u32*)&o;
#pragma unroll
    for (int i = 0; i < 4; ++i)
        ou[i] = pk2(acc[2 * i] * sc, acc[2 * i + 1] * sc);
    int bh = row >> 11, n = row & 2047;
    int b = bh >> 3, h = bh & 7;
    *(uint4*)&ao[((size_t)(b * SEQ + n)) * EMB + h * HD + ch * 8] = o;
}

// ---------------- launch ----------------

extern "C" void kernel_launch(void* const* d_in, const int* in_sizes, int n_in,
                              void* d_out, int out_size, void* d_ws, size_t ws_size,
                              hipStream_t stream) {
    const float* x     = (const float*)d_in[0];
    const float* Wqkv  = (const float*)d_in[1];
    const float* bqkv  = (const float*)d_in[2];
    const float* Wproj = (const float*)d_in[3];
    const float* bproj = (const float*)d_in[4];
    float* out = (float*)d_out;

    // workspace: persistent buffers, then a union region (xb/wqkT/wvr alias partb:
    // xb & weights are dead once attn starts; partb is written by attn).
    // NOTE: wvr MUST stay contiguous right after wqkT — gemm_qkv treats them as one
    // 2304-row B^T matrix.
    char* p = (char*)d_ws;
    u16*   qb    = (u16*)p;  p += (size_t)NROWS * HD * 2;          // 12.6 MB
    u16*   kg    = (u16*)p;  p += (size_t)NROWS * 128 * 2;         // 16.8 MB
    u16*   vt    = (u16*)p;  p += (size_t)NROWS * HD * 2;          // 12.6 MB
    u16*   ao    = (u16*)p;  p += (size_t)MTOK * EMB * 2;          // 12.6 MB
    u16*   wpt   = (u16*)p;  p += (size_t)EMB * EMB * 2;           // 1.2 MB
    float* lpart = (float*)p; p += (size_t)KSPLIT * NROWS * 4;     // 1.05 MB
    char*  U     = p;                                              // union region
    u16*   xb    = (u16*)U;
    u16*   wqkT  = (u16*)(U + (size_t)MTOK * EMB * 2);
    u16*   wvr   = (u16*)(U + (size_t)MTOK * EMB * 2 + (size_t)1536 * EMB * 2);
    u16*   partb = (u16*)U;                                        // 50.3 MB

    prep_kernel<<<3648, 256, 0, stream>>>(x, Wqkv, Wproj, xb, wqkT, wvr, wpt);
    gemm_qkv_kernel<<<dim3(E3 / 128, MTOK / 128), 256, 0, stream>>>(xb, wqkT, bqkv, qb, kg, vt);
    attn_kernel<<<8 * 32 * KSPLIT, 512, 0, stream>>>(qb, kg, vt, partb, lpart);
    combine_kernel<<<NROWS * 12 / 256, 256, 0, stream>>>(partb, lpart, ao);
    gemm_proj_kernel<<<dim3(EMB / 64, MTOK / 128), 256, 0, stream>>>(ao, wpt, bproj, out);
}

// Round 9
// 230.799 us; speedup vs baseline: 1.3399x; 1.0268x over previous
//
#include <hip/hip_runtime.h>
#include <cstdint>

#define BB 4
#define SEQ 2048
#define EMB 768
#define NH 8
#define HD 96
#define E3 2304
#define MTOK 8192
#define NROWS 65536            // BB*NH*SEQ
#define KSPLIT 4
#define SCALING 0.10206207261596575f
#define LOG2E 1.44269504f

typedef unsigned short u16;
typedef unsigned int u32;
typedef __bf16 bf16x8 __attribute__((ext_vector_type(8)));
typedef float f32x4 __attribute__((ext_vector_type(4)));
typedef float f32x16 __attribute__((ext_vector_type(16)));

__device__ __forceinline__ u16 f2bf(float f) {
    union { float f; uint32_t u; } c; c.f = f;
    uint32_t u = c.u;
    return (u16)((u + 0x7FFFu + ((u >> 16) & 1u)) >> 16);
}
__device__ __forceinline__ uint32_t pk2(float a, float b) {
    return (uint32_t)f2bf(a) | ((uint32_t)f2bf(b) << 16);
}
__device__ __forceinline__ uint32_t cvtpk(float a, float b) {
    uint32_t r;
    asm("v_cvt_pk_bf16_f32 %0, %1, %2" : "=v"(r) : "v"(a), "v"(b));
    return r;
}
__device__ __forceinline__ float bf2f(u16 h) {
    union { uint32_t u; float f; } c; c.u = ((uint32_t)h) << 16; return c.f;
}
__device__ __forceinline__ float fexp2(float x) {
    return __builtin_amdgcn_exp2f(x);
}
__device__ __forceinline__ void async16(const u16* g, u16* l) {
    __builtin_amdgcn_global_load_lds(
        (const __attribute__((address_space(1))) void*)g,
        (__attribute__((address_space(3))) void*)l, 16, 0, 0);
}

// ---------------- fused prep: cvt_x + 3 weight transposes, one launch ----------------

__device__ __forceinline__ void transpose_body(const float* __restrict__ src,
                                               u16* __restrict__ dst,
                                               int ncols, int mode, int j0, int k0,
                                               int tid, float (*T)[65]) {
#pragma unroll
    for (int it = 0; it < 16; ++it) {
        int lin = it * 256 + tid;
        int rr2 = lin >> 6, jj = lin & 63;
        int j = j0 + jj;
        int c;
        if (mode == 0) c = j;
        else if (mode == 1) { int s = j / 768, rr = j % 768; c = (rr / 96) * 288 + (rr % 96) * 3 + s; }
        else { c = (j / 96) * 288 + (j % 96) * 3 + 2; }
        T[rr2][jj] = src[(k0 + rr2) * ncols + c];
    }
    __syncthreads();
#pragma unroll
    for (int it = 0; it < 16; ++it) {
        int lin = it * 256 + tid;
        int jr = lin >> 6, kc = lin & 63;
        dst[(size_t)(j0 + jr) * 768 + k0 + kc] = f2bf(T[kc][jr]);
    }
}

__global__ __launch_bounds__(256) void prep_kernel(const float* __restrict__ x,
                                                   const float* __restrict__ Wqkv,
                                                   const float* __restrict__ Wproj,
                                                   u16* __restrict__ xb,
                                                   u16* __restrict__ wqkT,
                                                   u16* __restrict__ wvr,
                                                   u16* __restrict__ wpt) {
    __shared__ float T[64][65];
    int bid = blockIdx.x, tid = threadIdx.x;
    if (bid < 3072) {
        int i = bid * 256 + tid;                    // 786432 chunks of 8 floats
        const float4* s4 = (const float4*)x;
        float4 a = s4[2 * i];
        float4 c = s4[2 * i + 1];
        uint4 o;
        o.x = pk2(a.x, a.y); o.y = pk2(a.z, a.w);
        o.z = pk2(c.x, c.y); o.w = pk2(c.z, c.w);
        ((uint4*)xb)[i] = o;
    } else if (bid < 3360) {
        int t = bid - 3072;
        transpose_body(Wqkv, wqkT, E3, 1, (t % 24) * 64, (t / 24) * 64, tid, T);
    } else if (bid < 3504) {
        int t = bid - 3360;
        transpose_body(Wqkv, wvr, E3, 2, (t % 12) * 64, (t / 12) * 64, tid, T);
    } else {
        int t = bid - 3504;
        transpose_body(Wproj, wpt, EMB, 0, (t % 12) * 64, (t / 12) * 64, tid, T);
    }
}

// ---------------- NT-GEMM mainloops: global_load_lds + XOR-swizzled LDS ----------------

// 128x128 tile
__device__ __forceinline__ void gemm_tiles(const u16* __restrict__ A,
                                           const u16* __restrict__ Bt,
                                           int m0, int n0, int tid,
                                           u16* As, u16* Bs, f32x4 acc[4][4]) {
    const int lane = tid & 63;
    const int w = tid >> 6;
    const int l15 = lane & 15;
    const int quad = lane >> 4;
    const int wr = (w >> 1) * 64;
    const int wc = (w & 1) * 64;
    const int swz = l15 & 7;
    for (int kb = 0; kb < 768; kb += 64) {
#pragma unroll
        for (int it = 0; it < 4; ++it) {
            int base = (w * 4 + it) * 64;
            int lin = base + lane;
            int row = lin >> 3, cl = lin & 7;
            int cg = cl ^ (row & 7);
            async16(&A[(size_t)(m0 + row) * 768 + kb + cg * 8], &As[base * 8]);
            async16(&Bt[(size_t)(n0 + row) * 768 + kb + cg * 8], &Bs[base * 8]);
        }
        __syncthreads();
#pragma unroll
        for (int ks = 0; ks < 2; ++ks) {
            bf16x8 af[4], bfg[4];
#pragma unroll
            for (int fi = 0; fi < 4; ++fi)
                af[fi] = *(const bf16x8*)&As[(wr + fi * 16 + l15) * 64 + (((ks * 4 + quad) ^ swz) * 8)];
#pragma unroll
            for (int fj = 0; fj < 4; ++fj)
                bfg[fj] = *(const bf16x8*)&Bs[(wc + fj * 16 + l15) * 64 + (((ks * 4 + quad) ^ swz) * 8)];
#pragma unroll
            for (int fi = 0; fi < 4; ++fi)
#pragma unroll
                for (int fj = 0; fj < 4; ++fj)
                    acc[fi][fj] = __builtin_amdgcn_mfma_f32_16x16x32_bf16(af[fi], bfg[fj], acc[fi][fj], 0, 0, 0);
        }
        __syncthreads();
    }
}

// 128x64 tile (skinny-N GEMMs)
__device__ __forceinline__ void gemm_tiles64(const u16* __restrict__ A,
                                             const u16* __restrict__ Bt,
                                             int m0, int n0, int tid,
                                             u16* As, u16* Bs, f32x4 acc[4][2]) {
    const int lane = tid & 63;
    const int w = tid >> 6;
    const int l15 = lane & 15;
    const int quad = lane >> 4;
    const int wr = (w >> 1) * 64;
    const int wc = (w & 1) * 32;
    const int swz = l15 & 7;
    for (int kb = 0; kb < 768; kb += 64) {
#pragma unroll
        for (int it = 0; it < 4; ++it) {
            int base = (w * 4 + it) * 64;
            int lin = base + lane;
            int row = lin >> 3, cl = lin & 7;
            int cg = cl ^ (row & 7);
            async16(&A[(size_t)(m0 + row) * 768 + kb + cg * 8], &As[base * 8]);
        }
#pragma unroll
        for (int it = 0; it < 2; ++it) {
            int base = (w * 2 + it) * 64;
            int lin = base + lane;
            int row = lin >> 3, cl = lin & 7;
            int cg = cl ^ (row & 7);
            async16(&Bt[(size_t)(n0 + row) * 768 + kb + cg * 8], &Bs[base * 8]);
        }
        __syncthreads();
#pragma unroll
        for (int ks = 0; ks < 2; ++ks) {
            bf16x8 af[4], bfg[2];
#pragma unroll
            for (int fi = 0; fi < 4; ++fi)
                af[fi] = *(const bf16x8*)&As[(wr + fi * 16 + l15) * 64 + (((ks * 4 + quad) ^ swz) * 8)];
#pragma unroll
            for (int fj = 0; fj < 2; ++fj)
                bfg[fj] = *(const bf16x8*)&Bs[(wc + fj * 16 + l15) * 64 + (((ks * 4 + quad) ^ swz) * 8)];
#pragma unroll
            for (int fi = 0; fi < 4; ++fi)
#pragma unroll
                for (int fj = 0; fj < 2; ++fj)
                    acc[fi][fj] = __builtin_amdgcn_mfma_f32_16x16x32_bf16(af[fi], bfg[fj], acc[fi][fj], 0, 0, 0);
        }
        __syncthreads();
    }
}

// Unified QKV projection: ONE NT-GEMM M=8192 x N=2304 x K=768 in 128x128 tiles.
// R9: + T1 XCD-chunked block swizzle. Default dispatch round-robins linear ids over
// the 8 XCDs, so blocks sharing an A-row panel scatter -> each XCD's L2 re-fetches
// the full 12.6 MB A. Bijective remap (1152%8==0): XCD x owns wgid in [144x,144x+144)
// = 8 contiguous m-panels x all 18 n -> per-XCD A slice 1.5 MB (L2-resident), B 3.5 MB
// streams with high reuse. Internals unchanged.
__global__ __launch_bounds__(256) void gemm_qkv_kernel(const u16* __restrict__ xb,
                                                       const u16* __restrict__ wqkT,
                                                       const float* __restrict__ bqkv,
                                                       u16* __restrict__ qb,
                                                       u16* __restrict__ kg,
                                                       u16* __restrict__ vt) {
    __shared__ __align__(16) u16 As[128 * 64];
    __shared__ __align__(16) u16 Bs[128 * 64];
    int tid = threadIdx.x;
    int id = blockIdx.x + 18 * blockIdx.y;          // hardware linear id (x fastest)
    int wgid = (id & 7) * 144 + (id >> 3);          // bijective XCD chunking
    int n0 = (wgid % 18) * 128, m0 = (wgid / 18) * 128;
    f32x4 acc[4][4] = {};
    gemm_tiles(xb, wqkT, m0, n0, tid, As, Bs, acc);
    int lane = tid & 63, w = tid >> 6, l15 = lane & 15, quad = lane >> 4;
    int wr = (w >> 1) * 64, wc = (w & 1) * 64;
    if (n0 < 1536) {
        // ---- Q/K path: Q pre-scaled by LOG2E -> qb[bh][n][96]; K -> kg chunk-swizzled.
#pragma unroll
        for (int fj = 0; fj < 4; ++fj) {
            int j = n0 + wc + fj * 16 + l15;
            int s = j / 768, rr = j % 768;
            int hh = rr / 96, dd = rr % 96;
            float bv = bqkv[hh * 288 + dd * 3 + s];
#pragma unroll
            for (int fi = 0; fi < 4; ++fi) {
#pragma unroll
                for (int r = 0; r < 4; ++r) {
                    int m = m0 + wr + fi * 16 + quad * 4 + r;
                    int b = m >> 11, n = m & 2047;
                    int bh = b * NH + hh;
                    float v = acc[fi][fj][r] + bv;
                    if (s == 0) {
                        qb[((size_t)bh * SEQ + n) * HD + dd] = f2bf(v * LOG2E);
                    } else {
                        int cp = (dd >> 3) ^ (n & 7);
                        kg[((size_t)bh * SEQ + n) * 128 + cp * 8 + (dd & 7)] = f2bf(v);
                    }
                }
            }
        }
    } else {
        // ---- V path: channel c = j-1536 -> (hh,dd); token m -> chunk-swizzled kk.
#pragma unroll
        for (int fj = 0; fj < 4; ++fj) {
            int c = n0 + wc + fj * 16 + l15 - 1536;
            int hh = c / 96, dd = c % 96;
            float bv = bqkv[hh * 288 + dd * 3 + 2];
            size_t rowb = ((size_t)hh * HD + dd) * SEQ;   // + b*NH*HD*SEQ below
#pragma unroll
            for (int fi = 0; fi < 4; ++fi) {
#pragma unroll
                for (int r = 0; r < 4; ++r) {
                    int m = m0 + wr + fi * 16 + quad * 4 + r;
                    int b = m >> 11, nn = m & 2047;
                    int kk = (nn & ~63) | ((((nn >> 3) ^ dd) & 7) << 3) | (nn & 7);
                    vt[(size_t)b * NH * HD * SEQ + rowb + kk] =
                        f2bf(acc[fi][fj][r] + bv);
                }
            }
        }
    }
}

// out projection: 128(M)x64(N) tiles, grid 12x64 = 768 = 3/CU even.
// R9: + T1 XCD-chunked swizzle (768%8==0): XCD x owns 8 contiguous m-panels
// -> per-XCD working set = A slice 1.5 MB + B 1.2 MB = 2.7 MB, fully L2-resident.
__global__ __launch_bounds__(256) void gemm_proj_kernel(const u16* __restrict__ A,
                                                        const u16* __restrict__ Bt,
                                                        const float* __restrict__ bias,
                                                        float* __restrict__ out) {
    __shared__ __align__(16) u16 As[128 * 64];
    __shared__ __align__(16) u16 Bs[64 * 64];
    int tid = threadIdx.x;
    int id = blockIdx.x + 12 * blockIdx.y;          // hardware linear id (x fastest)
    int wgid = (id & 7) * 96 + (id >> 3);           // bijective XCD chunking
    int n0 = (wgid % 12) * 64, m0 = (wgid / 12) * 128;
    f32x4 acc[4][2] = {};
    gemm_tiles64(A, Bt, m0, n0, tid, As, Bs, acc);
    int lane = tid & 63, w = tid >> 6, l15 = lane & 15, quad = lane >> 4;
    int wr = (w >> 1) * 64, wc = (w & 1) * 32;
#pragma unroll
    for (int fj = 0; fj < 2; ++fj) {
        int j = n0 + wc + fj * 16 + l15;
        float bv = bias[j];
#pragma unroll
        for (int fi = 0; fi < 4; ++fi) {
#pragma unroll
            for (int r = 0; r < 4; ++r) {
                int m = m0 + wr + fi * 16 + quad * 4 + r;
                out[(size_t)m * 768 + j] = acc[fi][fj][r] + bv;
            }
        }
    }
}

// ---------------- flash attention: 8 waves x 1 q-tile, 4-way K-split, XCD-pinned -----
// R6-verified structure (72.3-72.6 us), FROZEN (control for this round): single-
// buffered 28.5 KB LDS + lockstep barrier cadence IS the L2-reuse mechanism — R7's
// double-buffer broke slice-cohort lockstep and quintupled FETCH (62->334 MB, 150 us).
// 8 waves x 1 q-tile keeps VGPR at 64 (occupancy 35%, TLP-saturated per R6). Softmax:
// v_cvt_pk_bf16_f32 + v_permlane32_swap_b32 + s_setprio (R3). Grid idx = qt*128 +
// bh*4 + kh -> the 8 qt-blocks sharing a (bh,kh) K/V slice land on the same XCD.
__global__ __launch_bounds__(512, 4) void attn_kernel(const u16* __restrict__ Q,
                                                      const u16* __restrict__ Kg,
                                                      const u16* __restrict__ Vt,
                                                      u16* __restrict__ part,
                                                      float* __restrict__ lpart) {
    __shared__ __align__(16) u16 Ks[64 * 128];   // 16 KB
    __shared__ __align__(16) u16 Vs[96 * 64];    // 12 KB
    int tid = threadIdx.x;
    int lane = tid & 63, w = tid >> 6;           // w = 0..7
    int l31 = lane & 31, hf = lane >> 5;
    int swz = l31 & 7;
    int bid = blockIdx.x;
    int qt = bid >> 7;                 // 0..7
    int g = bid & 127;
    int bh = g >> 2, kh = g & 3;       // (bh,kh) fixed -> idx%8 fixed -> same XCD
    const u16* qp = Q + (size_t)bh * SEQ * HD;
    const u16* kgp = Kg + (size_t)bh * SEQ * 128;
    const u16* vtp = Vt + (size_t)bh * HD * SEQ;
    int qbase = qt * 256 + w * 32;     // each wave owns ONE 32-q tile
    int kbase = kh * 512;

    // Q B-operand frags: 6 d-chunks, in registers for whole kernel
    bf16x8 aq[6];
#pragma unroll
    for (int dc = 0; dc < 6; ++dc)
        aq[dc] = *(const bf16x8*)&qp[(size_t)(qbase + l31) * HD + dc * 16 + hf * 8];

    f32x16 Ot[3] = {};
    float lp = 0.f;

    for (int kt = 0; kt < 8; ++kt) {
        int k0 = kbase + kt * 64;
        // K: 16 chunks of 512 u16 over 8 waves
#pragma unroll
        for (int it = 0; it < 2; ++it) {
            int cw = w * 2 + it;
            async16(kgp + (size_t)(k0 + cw * 4 + (lane >> 4)) * 128 + (lane & 15) * 8,
                    &Ks[cw * 512]);
        }
        // V: 12 chunks of 512 u16 over 8 waves (waves 4..7 skip second issue)
#pragma unroll
        for (int it = 0; it < 2; ++it) {
            int vw = it * 8 + w;
            if (vw < 12)
                async16(vtp + (size_t)(vw * 8 + (lane >> 3)) * SEQ + k0 + (lane & 7) * 8,
                        &Vs[vw * 512]);
        }
        __syncthreads();

        // per 32-key group tau: S' -> exp -> permlane exchange -> PV
#pragma unroll
        for (int tau = 0; tau < 2; ++tau) {
            f32x16 Sv = {};
            __builtin_amdgcn_s_setprio(1);
#pragma unroll
            for (int dc = 0; dc < 6; ++dc) {
                bf16x8 ka = *(const bf16x8*)&Ks[(tau * 32 + l31) * 128 + (((2 * dc + hf) ^ swz) * 8)];
                Sv = __builtin_amdgcn_mfma_f32_32x32x16_bf16(ka, aq[dc], Sv, 0, 0, 0);
            }
            __builtin_amdgcn_s_setprio(0);
            u32 pk[4][2];
#pragma unroll
            for (int g2 = 0; g2 < 4; ++g2)
#pragma unroll
                for (int u = 0; u < 2; ++u) {
                    float a0 = fexp2(Sv[g2 * 4 + 2 * u]);
                    float a1 = fexp2(Sv[g2 * 4 + 2 * u + 1]);
                    lp += a0 + a1;
                    pk[g2][u] = cvtpk(a0, a1);
                }
            // cross-half exchange: v_permlane32_swap_b32(X=pk[2kc], Y=pk[2kc+1]) gives
            //   X' = pf words 0/1, Y' = pf words 2/3 for all lanes
#pragma unroll
            for (int kc = 0; kc < 2; ++kc)
#pragma unroll
                for (int u = 0; u < 2; ++u)
                    asm("v_permlane32_swap_b32 %0, %1"
                        : "+v"(pk[2 * kc][u]), "+v"(pk[2 * kc + 1][u]));
#pragma unroll
            for (int kc = 0; kc < 2; ++kc) {
                union { u32 u[4]; bf16x8 v; } pf;
                pf.u[0] = pk[2 * kc][0];     pf.u[1] = pk[2 * kc][1];
                pf.u[2] = pk[2 * kc + 1][0]; pf.u[3] = pk[2 * kc + 1][1];
                __builtin_amdgcn_s_setprio(1);
#pragma unroll
                for (int t = 0; t < 3; ++t) {
                    bf16x8 va = *(const bf16x8*)&Vs[(t * 32 + l31) * 64 + (((4 * tau + 2 * kc + hf) ^ swz) * 8)];
                    Ot[t] = __builtin_amdgcn_mfma_f32_32x32x16_bf16(va, pf.v, Ot[t], 0, 0, 0);
                }
                __builtin_amdgcn_s_setprio(0);
            }
        }
        __syncthreads();
    }

    // epilogue: bf16 partial O^T + f32 partial l
    size_t pb = (size_t)kh * NROWS + (size_t)bh * SEQ;
    {
        int q = qbase + l31;
        float lr = lp + __shfl_xor(lp, 32);
        if (hf == 0) lpart[pb + q] = lr;
        size_t rowb = (pb + q) * HD;
#pragma unroll
        for (int t = 0; t < 3; ++t) {
#pragma unroll
            for (int g2 = 0; g2 < 4; ++g2) {
                int d0 = t * 32 + 8 * g2 + 4 * hf;
                uint2 val;
                val.x = pk2(Ot[t][g2 * 4 + 0], Ot[t][g2 * 4 + 1]);
                val.y = pk2(Ot[t][g2 * 4 + 2], Ot[t][g2 * 4 + 3]);
                *(uint2*)&part[rowb + d0] = val;
            }
        }
    }
}

// combine: ao[b][n][h*96+d] = (sum_kh part_kh) * SCALING / (sum_kh l_kh)
__global__ __launch_bounds__(256) void combine_kernel(const u16* __restrict__ part,
                                                      const float* __restrict__ lpart,
                                                      u16* __restrict__ ao) {
    int idx = blockIdx.x * 256 + threadIdx.x;       // NROWS*12 threads
    int row = idx / 12, ch = idx % 12;
    float l = 0.f;
#pragma unroll
    for (int k = 0; k < KSPLIT; ++k) l += lpart[(size_t)k * NROWS + row];
    float sc = SCALING / l;
    float acc[8] = {};
#pragma unroll
    for (int k = 0; k < KSPLIT; ++k) {
        uint4 pv = *(const uint4*)&part[((size_t)k * NROWS + row) * HD + ch * 8];
        const u16* a = (const u16*)&pv;
#pragma unroll
        for (int i = 0; i < 8; ++i) acc[i] += bf2f(a[i]);
    }
    uint4 o;
    u32* ou = (u32*)&o;
#pragma unroll
    for (int i = 0; i < 4; ++i)
        ou[i] = pk2(acc[2 * i] * sc, acc[2 * i + 1] * sc);
    int bh = row >> 11, n = row & 2047;
    int b = bh >> 3, h = bh & 7;
    *(uint4*)&ao[((size_t)(b * SEQ + n)) * EMB + h * HD + ch * 8] = o;
}

// ---------------- launch ----------------

extern "C" void kernel_launch(void* const* d_in, const int* in_sizes, int n_in,
                              void* d_out, int out_size, void* d_ws, size_t ws_size,
                              hipStream_t stream) {
    const float* x     = (const float*)d_in[0];
    const float* Wqkv  = (const float*)d_in[1];
    const float* bqkv  = (const float*)d_in[2];
    const float* Wproj = (const float*)d_in[3];
    const float* bproj = (const float*)d_in[4];
    float* out = (float*)d_out;

    // workspace: persistent buffers, then a union region (xb/wqkT/wvr alias partb:
    // xb & weights are dead once attn starts; partb is written by attn).
    // NOTE: wvr MUST stay contiguous right after wqkT — gemm_qkv treats them as one
    // 2304-row B^T matrix.
    char* p = (char*)d_ws;
    u16*   qb    = (u16*)p;  p += (size_t)NROWS * HD * 2;          // 12.6 MB
    u16*   kg    = (u16*)p;  p += (size_t)NROWS * 128 * 2;         // 16.8 MB
    u16*   vt    = (u16*)p;  p += (size_t)NROWS * HD * 2;          // 12.6 MB
    u16*   ao    = (u16*)p;  p += (size_t)MTOK * EMB * 2;          // 12.6 MB
    u16*   wpt   = (u16*)p;  p += (size_t)EMB * EMB * 2;           // 1.2 MB
    float* lpart = (float*)p; p += (size_t)KSPLIT * NROWS * 4;     // 1.05 MB
    char*  U     = p;                                              // union region
    u16*   xb    = (u16*)U;
    u16*   wqkT  = (u16*)(U + (size_t)MTOK * EMB * 2);
    u16*   wvr   = (u16*)(U + (size_t)MTOK * EMB * 2 + (size_t)1536 * EMB * 2);
    u16*   partb = (u16*)U;                                        // 50.3 MB

    prep_kernel<<<3648, 256, 0, stream>>>(x, Wqkv, Wproj, xb, wqkT, wvr, wpt);
    gemm_qkv_kernel<<<dim3(E3 / 128, MTOK / 128), 256, 0, stream>>>(xb, wqkT, bqkv, qb, kg, vt);
    attn_kernel<<<8 * 32 * KSPLIT, 512, 0, stream>>>(qb, kg, vt, partb, lpart);
    combine_kernel<<<NROWS * 12 / 256, 256, 0, stream>>>(partb, lpart, ao);
    gemm_proj_kernel<<<dim3(EMB / 64, MTOK / 128), 256, 0, stream>>>(ao, wpt, bproj, out);
}

// Round 10
// 220.042 us; speedup vs baseline: 1.4054x; 1.0489x over previous
//
#include <hip/hip_runtime.h>
#include <cstdint>

#define BB 4
#define SEQ 2048
#define EMB 768
#define NH 8
#define HD 96
#define E3 2304
#define MTOK 8192
#define NROWS 65536            // BB*NH*SEQ
#define KSPLIT 2
#define SCALING 0.10206207261596575f
#define LOG2E 1.44269504f

typedef unsigned short u16;
typedef unsigned int u32;
typedef __bf16 bf16x8 __attribute__((ext_vector_type(8)));
typedef float f32x4 __attribute__((ext_vector_type(4)));
typedef float f32x16 __attribute__((ext_vector_type(16)));

__device__ __forceinline__ u16 f2bf(float f) {
    union { float f; uint32_t u; } c; c.f = f;
    uint32_t u = c.u;
    return (u16)((u + 0x7FFFu + ((u >> 16) & 1u)) >> 16);
}
__device__ __forceinline__ uint32_t pk2(float a, float b) {
    return (uint32_t)f2bf(a) | ((uint32_t)f2bf(b) << 16);
}
__device__ __forceinline__ uint32_t cvtpk(float a, float b) {
    uint32_t r;
    asm("v_cvt_pk_bf16_f32 %0, %1, %2" : "=v"(r) : "v"(a), "v"(b));
    return r;
}
__device__ __forceinline__ float bf2f(u16 h) {
    union { uint32_t u; float f; } c; c.u = ((uint32_t)h) << 16; return c.f;
}
__device__ __forceinline__ float fexp2(float x) {
    return __builtin_amdgcn_exp2f(x);
}
__device__ __forceinline__ void async16(const u16* g, u16* l) {
    __builtin_amdgcn_global_load_lds(
        (const __attribute__((address_space(1))) void*)g,
        (__attribute__((address_space(3))) void*)l, 16, 0, 0);
}

// ---------------- fused prep: cvt_x + 3 weight transposes, one launch ----------------

__device__ __forceinline__ void transpose_body(const float* __restrict__ src,
                                               u16* __restrict__ dst,
                                               int ncols, int mode, int j0, int k0,
                                               int tid, float (*T)[65]) {
#pragma unroll
    for (int it = 0; it < 16; ++it) {
        int lin = it * 256 + tid;
        int rr2 = lin >> 6, jj = lin & 63;
        int j = j0 + jj;
        int c;
        if (mode == 0) c = j;
        else if (mode == 1) { int s = j / 768, rr = j % 768; c = (rr / 96) * 288 + (rr % 96) * 3 + s; }
        else { c = (j / 96) * 288 + (j % 96) * 3 + 2; }
        T[rr2][jj] = src[(k0 + rr2) * ncols + c];
    }
    __syncthreads();
#pragma unroll
    for (int it = 0; it < 16; ++it) {
        int lin = it * 256 + tid;
        int jr = lin >> 6, kc = lin & 63;
        dst[(size_t)(j0 + jr) * 768 + k0 + kc] = f2bf(T[kc][jr]);
    }
}

__global__ __launch_bounds__(256) void prep_kernel(const float* __restrict__ x,
                                                   const float* __restrict__ Wqkv,
                                                   const float* __restrict__ Wproj,
                                                   u16* __restrict__ xb,
                                                   u16* __restrict__ wqkT,
                                                   u16* __restrict__ wvr,
                                                   u16* __restrict__ wpt) {
    __shared__ float T[64][65];
    int bid = blockIdx.x, tid = threadIdx.x;
    if (bid < 3072) {
        int i = bid * 256 + tid;                    // 786432 chunks of 8 floats
        const float4* s4 = (const float4*)x;
        float4 a = s4[2 * i];
        float4 c = s4[2 * i + 1];
        uint4 o;
        o.x = pk2(a.x, a.y); o.y = pk2(a.z, a.w);
        o.z = pk2(c.x, c.y); o.w = pk2(c.z, c.w);
        ((uint4*)xb)[i] = o;
    } else if (bid < 3360) {
        int t = bid - 3072;
        transpose_body(Wqkv, wqkT, E3, 1, (t % 24) * 64, (t / 24) * 64, tid, T);
    } else if (bid < 3504) {
        int t = bid - 3360;
        transpose_body(Wqkv, wvr, E3, 2, (t % 12) * 64, (t / 12) * 64, tid, T);
    } else {
        int t = bid - 3504;
        transpose_body(Wproj, wpt, EMB, 0, (t % 12) * 64, (t / 12) * 64, tid, T);
    }
}

// ---------------- NT-GEMM mainloops: global_load_lds + XOR-swizzled LDS ----------------

// 128x128 tile
__device__ __forceinline__ void gemm_tiles(const u16* __restrict__ A,
                                           const u16* __restrict__ Bt,
                                           int m0, int n0, int tid,
                                           u16* As, u16* Bs, f32x4 acc[4][4]) {
    const int lane = tid & 63;
    const int w = tid >> 6;
    const int l15 = lane & 15;
    const int quad = lane >> 4;
    const int wr = (w >> 1) * 64;
    const int wc = (w & 1) * 64;
    const int swz = l15 & 7;
    for (int kb = 0; kb < 768; kb += 64) {
#pragma unroll
        for (int it = 0; it < 4; ++it) {
            int base = (w * 4 + it) * 64;
            int lin = base + lane;
            int row = lin >> 3, cl = lin & 7;
            int cg = cl ^ (row & 7);
            async16(&A[(size_t)(m0 + row) * 768 + kb + cg * 8], &As[base * 8]);
            async16(&Bt[(size_t)(n0 + row) * 768 + kb + cg * 8], &Bs[base * 8]);
        }
        __syncthreads();
#pragma unroll
        for (int ks = 0; ks < 2; ++ks) {
            bf16x8 af[4], bfg[4];
#pragma unroll
            for (int fi = 0; fi < 4; ++fi)
                af[fi] = *(const bf16x8*)&As[(wr + fi * 16 + l15) * 64 + (((ks * 4 + quad) ^ swz) * 8)];
#pragma unroll
            for (int fj = 0; fj < 4; ++fj)
                bfg[fj] = *(const bf16x8*)&Bs[(wc + fj * 16 + l15) * 64 + (((ks * 4 + quad) ^ swz) * 8)];
#pragma unroll
            for (int fi = 0; fi < 4; ++fi)
#pragma unroll
                for (int fj = 0; fj < 4; ++fj)
                    acc[fi][fj] = __builtin_amdgcn_mfma_f32_16x16x32_bf16(af[fi], bfg[fj], acc[fi][fj], 0, 0, 0);
        }
        __syncthreads();
    }
}

// 128x64 tile (skinny-N GEMMs)
__device__ __forceinline__ void gemm_tiles64(const u16* __restrict__ A,
                                             const u16* __restrict__ Bt,
                                             int m0, int n0, int tid,
                                             u16* As, u16* Bs, f32x4 acc[4][2]) {
    const int lane = tid & 63;
    const int w = tid >> 6;
    const int l15 = lane & 15;
    const int quad = lane >> 4;
    const int wr = (w >> 1) * 64;
    const int wc = (w & 1) * 32;
    const int swz = l15 & 7;
    for (int kb = 0; kb < 768; kb += 64) {
#pragma unroll
        for (int it = 0; it < 4; ++it) {
            int base = (w * 4 + it) * 64;
            int lin = base + lane;
            int row = lin >> 3, cl = lin & 7;
            int cg = cl ^ (row & 7);
            async16(&A[(size_t)(m0 + row) * 768 + kb + cg * 8], &As[base * 8]);
        }
#pragma unroll
        for (int it = 0; it < 2; ++it) {
            int base = (w * 2 + it) * 64;
            int lin = base + lane;
            int row = lin >> 3, cl = lin & 7;
            int cg = cl ^ (row & 7);
            async16(&Bt[(size_t)(n0 + row) * 768 + kb + cg * 8], &Bs[base * 8]);
        }
        __syncthreads();
#pragma unroll
        for (int ks = 0; ks < 2; ++ks) {
            bf16x8 af[4], bfg[2];
#pragma unroll
            for (int fi = 0; fi < 4; ++fi)
                af[fi] = *(const bf16x8*)&As[(wr + fi * 16 + l15) * 64 + (((ks * 4 + quad) ^ swz) * 8)];
#pragma unroll
            for (int fj = 0; fj < 2; ++fj)
                bfg[fj] = *(const bf16x8*)&Bs[(wc + fj * 16 + l15) * 64 + (((ks * 4 + quad) ^ swz) * 8)];
#pragma unroll
            for (int fi = 0; fi < 4; ++fi)
#pragma unroll
                for (int fj = 0; fj < 2; ++fj)
                    acc[fi][fj] = __builtin_amdgcn_mfma_f32_16x16x32_bf16(af[fi], bfg[fj], acc[fi][fj], 0, 0, 0);
        }
        __syncthreads();
    }
}

// Unified QKV projection: ONE NT-GEMM M=8192 x N=2304 x K=768 in 128x128 tiles.
// R9-verified: + T1 XCD-chunked block swizzle (total 237 -> 230.8 with proj swizzle).
__global__ __launch_bounds__(256) void gemm_qkv_kernel(const u16* __restrict__ xb,
                                                       const u16* __restrict__ wqkT,
                                                       const float* __restrict__ bqkv,
                                                       u16* __restrict__ qb,
                                                       u16* __restrict__ kg,
                                                       u16* __restrict__ vt) {
    __shared__ __align__(16) u16 As[128 * 64];
    __shared__ __align__(16) u16 Bs[128 * 64];
    int tid = threadIdx.x;
    int id = blockIdx.x + 18 * blockIdx.y;          // hardware linear id (x fastest)
    int wgid = (id & 7) * 144 + (id >> 3);          // bijective XCD chunking
    int n0 = (wgid % 18) * 128, m0 = (wgid / 18) * 128;
    f32x4 acc[4][4] = {};
    gemm_tiles(xb, wqkT, m0, n0, tid, As, Bs, acc);
    int lane = tid & 63, w = tid >> 6, l15 = lane & 15, quad = lane >> 4;
    int wr = (w >> 1) * 64, wc = (w & 1) * 64;
    if (n0 < 1536) {
        // ---- Q/K path: Q pre-scaled by LOG2E -> qb[bh][n][96]; K -> kg chunk-swizzled.
#pragma unroll
        for (int fj = 0; fj < 4; ++fj) {
            int j = n0 + wc + fj * 16 + l15;
            int s = j / 768, rr = j % 768;
            int hh = rr / 96, dd = rr % 96;
            float bv = bqkv[hh * 288 + dd * 3 + s];
#pragma unroll
            for (int fi = 0; fi < 4; ++fi) {
#pragma unroll
                for (int r = 0; r < 4; ++r) {
                    int m = m0 + wr + fi * 16 + quad * 4 + r;
                    int b = m >> 11, n = m & 2047;
                    int bh = b * NH + hh;
                    float v = acc[fi][fj][r] + bv;
                    if (s == 0) {
                        qb[((size_t)bh * SEQ + n) * HD + dd] = f2bf(v * LOG2E);
                    } else {
                        int cp = (dd >> 3) ^ (n & 7);
                        kg[((size_t)bh * SEQ + n) * 128 + cp * 8 + (dd & 7)] = f2bf(v);
                    }
                }
            }
        }
    } else {
        // ---- V path: channel c = j-1536 -> (hh,dd); token m -> chunk-swizzled kk.
#pragma unroll
        for (int fj = 0; fj < 4; ++fj) {
            int c = n0 + wc + fj * 16 + l15 - 1536;
            int hh = c / 96, dd = c % 96;
            float bv = bqkv[hh * 288 + dd * 3 + 2];
            size_t rowb = ((size_t)hh * HD + dd) * SEQ;   // + b*NH*HD*SEQ below
#pragma unroll
            for (int fi = 0; fi < 4; ++fi) {
#pragma unroll
                for (int r = 0; r < 4; ++r) {
                    int m = m0 + wr + fi * 16 + quad * 4 + r;
                    int b = m >> 11, nn = m & 2047;
                    int kk = (nn & ~63) | ((((nn >> 3) ^ dd) & 7) << 3) | (nn & 7);
                    vt[(size_t)b * NH * HD * SEQ + rowb + kk] =
                        f2bf(acc[fi][fj][r] + bv);
                }
            }
        }
    }
}

// out projection: 128(M)x64(N) tiles + T1 XCD-chunked swizzle (R9-verified).
__global__ __launch_bounds__(256) void gemm_proj_kernel(const u16* __restrict__ A,
                                                        const u16* __restrict__ Bt,
                                                        const float* __restrict__ bias,
                                                        float* __restrict__ out) {
    __shared__ __align__(16) u16 As[128 * 64];
    __shared__ __align__(16) u16 Bs[64 * 64];
    int tid = threadIdx.x;
    int id = blockIdx.x + 12 * blockIdx.y;          // hardware linear id (x fastest)
    int wgid = (id & 7) * 96 + (id >> 3);           // bijective XCD chunking
    int n0 = (wgid % 12) * 64, m0 = (wgid / 12) * 128;
    f32x4 acc[4][2] = {};
    gemm_tiles64(A, Bt, m0, n0, tid, As, Bs, acc);
    int lane = tid & 63, w = tid >> 6, l15 = lane & 15, quad = lane >> 4;
    int wr = (w >> 1) * 64, wc = (w & 1) * 32;
#pragma unroll
    for (int fj = 0; fj < 2; ++fj) {
        int j = n0 + wc + fj * 16 + l15;
        float bv = bias[j];
#pragma unroll
        for (int fi = 0; fi < 4; ++fi) {
#pragma unroll
            for (int r = 0; r < 4; ++r) {
                int m = m0 + wr + fi * 16 + quad * 4 + r;
                out[(size_t)m * 768 + j] = acc[fi][fj][r] + bv;
            }
        }
    }
}

// ---------------- flash attention: 8 waves x 1 q-tile, 2-way K-split, XCD-pinned -----
// R10: KSPLIT 4 -> 2. R6 showed TLP saturates ~11 waves/CU; at KSPLIT=2 the grid is
// 512 blocks = 2 blocks/CU x 8 waves = 16 waves/CU (still saturated), each block does
// 16 K-tiles over keys [kh*1024, +1024). Halves the partial-sum HBM round-trip:
// attn writes 25 MB (was 50), combine reads 25.5 (was 50.5). XCD/L2 invariants hold:
// bid = qt*64 + bh*2 + kh -> bid%8 = (2bh+kh)%8 fixed per slice (64==0 mod 8); per-XCD
// working set = 8 slices x 448 KB = 3.6 MB < 4 MB L2; all 512 blocks co-resident ->
// lockstep cadence preserved. Per-tile structure FROZEN (R6-verified; R7's dbuf broke
// L2 and quintupled FETCH). Softmax: cvt_pk + permlane32_swap + setprio (R3).
__global__ __launch_bounds__(512, 4) void attn_kernel(const u16* __restrict__ Q,
                                                      const u16* __restrict__ Kg,
                                                      const u16* __restrict__ Vt,
                                                      u16* __restrict__ part,
                                                      float* __restrict__ lpart) {
    __shared__ __align__(16) u16 Ks[64 * 128];   // 16 KB
    __shared__ __align__(16) u16 Vs[96 * 64];    // 12 KB
    int tid = threadIdx.x;
    int lane = tid & 63, w = tid >> 6;           // w = 0..7
    int l31 = lane & 31, hf = lane >> 5;
    int swz = l31 & 7;
    int bid = blockIdx.x;
    int qt = bid >> 6;                 // 0..7
    int g = bid & 63;
    int bh = g >> 1, kh = g & 1;       // (bh,kh) fixed -> bid%8 fixed -> same XCD
    const u16* qp = Q + (size_t)bh * SEQ * HD;
    const u16* kgp = Kg + (size_t)bh * SEQ * 128;
    const u16* vtp = Vt + (size_t)bh * HD * SEQ;
    int qbase = qt * 256 + w * 32;     // each wave owns ONE 32-q tile
    int kbase = kh * 1024;

    // Q B-operand frags: 6 d-chunks, in registers for whole kernel
    bf16x8 aq[6];
#pragma unroll
    for (int dc = 0; dc < 6; ++dc)
        aq[dc] = *(const bf16x8*)&qp[(size_t)(qbase + l31) * HD + dc * 16 + hf * 8];

    f32x16 Ot[3] = {};
    float lp = 0.f;

    for (int kt = 0; kt < 16; ++kt) {
        int k0 = kbase + kt * 64;
        // K: 16 chunks of 512 u16 over 8 waves
#pragma unroll
        for (int it = 0; it < 2; ++it) {
            int cw = w * 2 + it;
            async16(kgp + (size_t)(k0 + cw * 4 + (lane >> 4)) * 128 + (lane & 15) * 8,
                    &Ks[cw * 512]);
        }
        // V: 12 chunks of 512 u16 over 8 waves (waves 4..7 skip second issue)
#pragma unroll
        for (int it = 0; it < 2; ++it) {
            int vw = it * 8 + w;
            if (vw < 12)
                async16(vtp + (size_t)(vw * 8 + (lane >> 3)) * SEQ + k0 + (lane & 7) * 8,
                        &Vs[vw * 512]);
        }
        __syncthreads();

        // per 32-key group tau: S' -> exp -> permlane exchange -> PV
#pragma unroll
        for (int tau = 0; tau < 2; ++tau) {
            f32x16 Sv = {};
            __builtin_amdgcn_s_setprio(1);
#pragma unroll
            for (int dc = 0; dc < 6; ++dc) {
                bf16x8 ka = *(const bf16x8*)&Ks[(tau * 32 + l31) * 128 + (((2 * dc + hf) ^ swz) * 8)];
                Sv = __builtin_amdgcn_mfma_f32_32x32x16_bf16(ka, aq[dc], Sv, 0, 0, 0);
            }
            __builtin_amdgcn_s_setprio(0);
            u32 pk[4][2];
#pragma unroll
            for (int g2 = 0; g2 < 4; ++g2)
#pragma unroll
                for (int u = 0; u < 2; ++u) {
                    float a0 = fexp2(Sv[g2 * 4 + 2 * u]);
                    float a1 = fexp2(Sv[g2 * 4 + 2 * u + 1]);
                    lp += a0 + a1;
                    pk[g2][u] = cvtpk(a0, a1);
                }
            // cross-half exchange: v_permlane32_swap_b32(X=pk[2kc], Y=pk[2kc+1]) gives
            //   X' = pf words 0/1, Y' = pf words 2/3 for all lanes
#pragma unroll
            for (int kc = 0; kc < 2; ++kc)
#pragma unroll
                for (int u = 0; u < 2; ++u)
                    asm("v_permlane32_swap_b32 %0, %1"
                        : "+v"(pk[2 * kc][u]), "+v"(pk[2 * kc + 1][u]));
#pragma unroll
            for (int kc = 0; kc < 2; ++kc) {
                union { u32 u[4]; bf16x8 v; } pf;
                pf.u[0] = pk[2 * kc][0];     pf.u[1] = pk[2 * kc][1];
                pf.u[2] = pk[2 * kc + 1][0]; pf.u[3] = pk[2 * kc + 1][1];
                __builtin_amdgcn_s_setprio(1);
#pragma unroll
                for (int t = 0; t < 3; ++t) {
                    bf16x8 va = *(const bf16x8*)&Vs[(t * 32 + l31) * 64 + (((4 * tau + 2 * kc + hf) ^ swz) * 8)];
                    Ot[t] = __builtin_amdgcn_mfma_f32_32x32x16_bf16(va, pf.v, Ot[t], 0, 0, 0);
                }
                __builtin_amdgcn_s_setprio(0);
            }
        }
        __syncthreads();
    }

    // epilogue: bf16 partial O^T + f32 partial l
    size_t pb = (size_t)kh * NROWS + (size_t)bh * SEQ;
    {
        int q = qbase + l31;
        float lr = lp + __shfl_xor(lp, 32);
        if (hf == 0) lpart[pb + q] = lr;
        size_t rowb = (pb + q) * HD;
#pragma unroll
        for (int t = 0; t < 3; ++t) {
#pragma unroll
            for (int g2 = 0; g2 < 4; ++g2) {
                int d0 = t * 32 + 8 * g2 + 4 * hf;
                uint2 val;
                val.x = pk2(Ot[t][g2 * 4 + 0], Ot[t][g2 * 4 + 1]);
                val.y = pk2(Ot[t][g2 * 4 + 2], Ot[t][g2 * 4 + 3]);
                *(uint2*)&part[rowb + d0] = val;
            }
        }
    }
}

// combine: ao[b][n][h*96+d] = (sum_kh part_kh) * SCALING / (sum_kh l_kh)
__global__ __launch_bounds__(256) void combine_kernel(const u16* __restrict__ part,
                                                      const float* __restrict__ lpart,
                                                      u16* __restrict__ ao) {
    int idx = blockIdx.x * 256 + threadIdx.x;       // NROWS*12 threads
    int row = idx / 12, ch = idx % 12;
    float l = 0.f;
#pragma unroll
    for (int k = 0; k < KSPLIT; ++k) l += lpart[(size_t)k * NROWS + row];
    float sc = SCALING / l;
    float acc[8] = {};
#pragma unroll
    for (int k = 0; k < KSPLIT; ++k) {
        uint4 pv = *(const uint4*)&part[((size_t)k * NROWS + row) * HD + ch * 8];
        const u16* a = (const u16*)&pv;
#pragma unroll
        for (int i = 0; i < 8; ++i) acc[i] += bf2f(a[i]);
    }
    uint4 o;
    u32* ou = (u32*)&o;
#pragma unroll
    for (int i = 0; i < 4; ++i)
        ou[i] = pk2(acc[2 * i] * sc, acc[2 * i + 1] * sc);
    int bh = row >> 11, n = row & 2047;
    int b = bh >> 3, h = bh & 7;
    *(uint4*)&ao[((size_t)(b * SEQ + n)) * EMB + h * HD + ch * 8] = o;
}

// ---------------- launch ----------------

extern "C" void kernel_launch(void* const* d_in, const int* in_sizes, int n_in,
                              void* d_out, int out_size, void* d_ws, size_t ws_size,
                              hipStream_t stream) {
    const float* x     = (const float*)d_in[0];
    const float* Wqkv  = (const float*)d_in[1];
    const float* bqkv  = (const float*)d_in[2];
    const float* Wproj = (const float*)d_in[3];
    const float* bproj = (const float*)d_in[4];
    float* out = (float*)d_out;

    // workspace: persistent buffers, then a union region (xb/wqkT/wvr alias partb:
    // xb & weights are dead once attn starts; partb is written by attn).
    // NOTE: wvr MUST stay contiguous right after wqkT — gemm_qkv treats them as one
    // 2304-row B^T matrix.
    char* p = (char*)d_ws;
    u16*   qb    = (u16*)p;  p += (size_t)NROWS * HD * 2;          // 12.6 MB
    u16*   kg    = (u16*)p;  p += (size_t)NROWS * 128 * 2;         // 16.8 MB
    u16*   vt    = (u16*)p;  p += (size_t)NROWS * HD * 2;          // 12.6 MB
    u16*   ao    = (u16*)p;  p += (size_t)MTOK * EMB * 2;          // 12.6 MB
    u16*   wpt   = (u16*)p;  p += (size_t)EMB * EMB * 2;           // 1.2 MB
    float* lpart = (float*)p; p += (size_t)KSPLIT * NROWS * 4;     // 0.5 MB
    char*  U     = p;                                              // union region
    u16*   xb    = (u16*)U;
    u16*   wqkT  = (u16*)(U + (size_t)MTOK * EMB * 2);
    u16*   wvr   = (u16*)(U + (size_t)MTOK * EMB * 2 + (size_t)1536 * EMB * 2);
    u16*   partb = (u16*)U;                                        // 25.2 MB

    prep_kernel<<<3648, 256, 0, stream>>>(x, Wqkv, Wproj, xb, wqkT, wvr, wpt);
    gemm_qkv_kernel<<<dim3(E3 / 128, MTOK / 128), 256, 0, stream>>>(xb, wqkT, bqkv, qb, kg, vt);
    attn_kernel<<<8 * 32 * KSPLIT, 512, 0, stream>>>(qb, kg, vt, partb, lpart);
    combine_kernel<<<NROWS * 12 / 256, 256, 0, stream>>>(partb, lpart, ao);
    gemm_proj_kernel<<<dim3(EMB / 64, MTOK / 128), 256, 0, stream>>>(ao, wpt, bproj, out);
}